// Round 4
// baseline (271.338 us; speedup 1.0000x reference)
//
#include <hip/hip_runtime.h>
#include <hip/hip_cooperative_groups.h>

namespace cg = cooperative_groups;

typedef __attribute__((ext_vector_type(8))) short short8;
typedef __attribute__((ext_vector_type(4))) float f32x4;

#define EPS   1e-3f
#define ALPHA 0.3f

__device__ __forceinline__ unsigned short f2bf(float f) {
    unsigned u = __float_as_uint(f);
    unsigned r = u + 0x7FFFu + ((u >> 16) & 1u);
    return (unsigned short)(r >> 16);
}
__device__ __forceinline__ float lrelu(float v) { return v > 0.f ? v : ALPHA * v; }

union SMem {
    struct { float Ms[1024 * 12]; float red[256]; } dv;   // 50176 B (diversity)
    struct { unsigned short At[32][296]; } hm;            // 18944 B (LN'd A-tile)
    struct { float rs[4], rq[4], rd[4]; } ln;             // final head
};

#define MFMA(a, b, c) __builtin_amdgcn_mfma_f32_16x16x32_bf16((a), (b), (c), 0, 0, 0)

// --------------------------------------------------------------------------
// hm tile: one 32x32 C-tile, A from global bf16 (ldk cols), B^T rows from L2.
// yt<8 -> h-GEMM (256 cols); yt in 8..11 -> M-GEMM (128 cols).
// --------------------------------------------------------------------------
__device__ __forceinline__ void hm_tile_global(
    const unsigned short* __restrict__ A, int ldk, int xt, int yt,
    const unsigned short* __restrict__ BTh, const float* __restrict__ biash,
    float* __restrict__ Ch,
    const unsigned short* __restrict__ BTm, const float* __restrict__ biasm,
    float* __restrict__ Cm)
{
    const int t = threadIdx.x, lane = t & 63, w = t >> 6;
    const int wr = w >> 1, wn = w & 1, r = lane & 15, g = lane >> 4;
    const bool isM = yt >= 8;
    const int colBase = (isM ? yt - 8 : yt) * 32 + wn * 16;
    const unsigned short* BT = isM ? BTm : BTh;
    const float* bias = isM ? biasm : biash;
    float* C = isM ? Cm : Ch;
    const int ldc = isM ? 128 : 256;
    const int arow = xt * 32 + wr * 16 + r;
    const int bcol = colBase + r;
    const unsigned short* Ap = A + (size_t)arow * ldk + g * 8;
    const unsigned short* Bp = BT + (size_t)bcol * ldk + g * 8;
    f32x4 acc0 = {0.f, 0.f, 0.f, 0.f}, acc1 = {0.f, 0.f, 0.f, 0.f};
    for (int k0 = 0; k0 < ldk; k0 += 64) {
        acc0 = MFMA(*(const short8*)(Ap + k0),      *(const short8*)(Bp + k0),      acc0);
        acc1 = MFMA(*(const short8*)(Ap + k0 + 32), *(const short8*)(Bp + k0 + 32), acc1);
    }
    f32x4 acc = acc0 + acc1;
    const float bv = bias[bcol];
    const int orow0 = xt * 32 + wr * 16 + g * 4;
#pragma unroll
    for (int i = 0; i < 4; ++i)
        C[(size_t)(orow0 + i) * ldc + bcol] = acc[i] + bv;
}

// --------------------------------------------------------------------------
// diversity job: (rt, k): 32 rows x one kernel slice. LDS [1024][12].
// --------------------------------------------------------------------------
__device__ __forceinline__ void div_job(SMem& sm, const float* __restrict__ M,
                                        float* __restrict__ divOut, int rt, int k)
{
    const int t = threadIdx.x;
    for (int idx = t; idx < 1024 * 5; idx += 256) {
        const int j = idx / 5;
        const int dd = idx - j * 5;
        const float2 v = *(const float2*)&M[(size_t)j * 128 + k * 10 + dd * 2];
        sm.dv.Ms[j * 12 + dd * 2]     = v.x;
        sm.dv.Ms[j * 12 + dd * 2 + 1] = v.y;
    }
    __syncthreads();
    const int il = t & 31, jc = t >> 5;
    const int i = rt * 32 + il;
    float Mi[10];
#pragma unroll
    for (int d = 0; d < 10; ++d) Mi[d] = sm.dv.Ms[i * 12 + d];
    float acc = 0.f;
    const int jB = jc * 128;
#pragma unroll 2
    for (int j = jB; j < jB + 128; ++j) {
        const float4 v0 = *(const float4*)&sm.dv.Ms[j * 12];
        const float4 v1 = *(const float4*)&sm.dv.Ms[j * 12 + 4];
        const float2 v2 = *(const float2*)&sm.dv.Ms[j * 12 + 8];
        float l1 = fabsf(Mi[0] - v0.x) + fabsf(Mi[1] - v0.y)
                 + fabsf(Mi[2] - v0.z) + fabsf(Mi[3] - v0.w)
                 + fabsf(Mi[4] - v1.x) + fabsf(Mi[5] - v1.y)
                 + fabsf(Mi[6] - v1.z) + fabsf(Mi[7] - v1.w)
                 + fabsf(Mi[8] - v2.x) + fabsf(Mi[9] - v2.y);
        acc += __expf(-l1);
    }
    sm.dv.red[t] = acc;
    __syncthreads();
    if (t < 32) {
        float s = 0.f;
#pragma unroll
        for (int c = 0; c < 8; ++c) s += sm.dv.red[c * 32 + t];
        divOut[(size_t)(rt * 32 + t) * 10 + k] = s;
    }
    __syncthreads();
}

// --------------------------------------------------------------------------
// LN0 stage: build LN'd+LeakyReLU'd bf16 A-tile [32][296] in LDS from h0/div0.
// Wave w handles rows w*8..w*8+7; full-wave shfl_xor reduce per row.
// --------------------------------------------------------------------------
__device__ __forceinline__ void ln_stage(SMem& sm, int xt,
    const float* __restrict__ h0, const float* __restrict__ div0,
    const float* __restrict__ beta0)
{
    const int t = threadIdx.x, lane = t & 63, w = t >> 6;
#pragma unroll 2
    for (int rr = 0; rr < 8; ++rr) {
        const int r = xt * 32 + w * 8 + rr;
        const float hv0 = h0[(size_t)r * 256 + lane];
        const float hv1 = h0[(size_t)r * 256 + 64 + lane];
        const float hv2 = h0[(size_t)r * 256 + 128 + lane];
        const float hv3 = h0[(size_t)r * 256 + 192 + lane];
        const float dvv = (lane < 10) ? div0[(size_t)r * 10 + lane] : 0.f;
        float s = hv0 + hv1 + hv2 + hv3 + dvv;
        float q = hv0 * hv0 + hv1 * hv1 + hv2 * hv2 + hv3 * hv3 + dvv * dvv;
#pragma unroll
        for (int m = 32; m > 0; m >>= 1) { s += __shfl_xor(s, m); q += __shfl_xor(q, m); }
        const float mean = s * (1.f / 266.f);
        const float var  = q * (1.f / 266.f) - mean * mean;
        const float inv  = rsqrtf(var + EPS);
        const int lr = w * 8 + rr;
        sm.hm.At[lr][lane]       = f2bf(lrelu((hv0 - mean) * inv + beta0[lane]));
        sm.hm.At[lr][64 + lane]  = f2bf(lrelu((hv1 - mean) * inv + beta0[64 + lane]));
        sm.hm.At[lr][128 + lane] = f2bf(lrelu((hv2 - mean) * inv + beta0[128 + lane]));
        sm.hm.At[lr][192 + lane] = f2bf(lrelu((hv3 - mean) * inv + beta0[192 + lane]));
        if (lane < 10)
            sm.hm.At[lr][256 + lane] = f2bf(lrelu((dvv - mean) * inv + beta0[256 + lane]));
        else if (lane < 32)
            sm.hm.At[lr][256 + lane] = 0;   // zero pad cols 266..287
    }
}

// --------------------------------------------------------------------------
// hm1 pass: MFMA over K=288, A from LDS tile, B^T rows from L2.
// --------------------------------------------------------------------------
__device__ __forceinline__ void hm1_pass(const SMem& sm, int xt, int yt,
    const unsigned short* __restrict__ W1bT, const float* __restrict__ b1,
    float* __restrict__ h1,
    const unsigned short* __restrict__ Wc1bT, const float* __restrict__ bcomb1,
    float* __restrict__ M1f)
{
    const int t = threadIdx.x, lane = t & 63, w = t >> 6;
    const int wr = w >> 1, wn = w & 1, r = lane & 15, g = lane >> 4;
    const bool isM = yt >= 8;
    const int colBase = (isM ? yt - 8 : yt) * 32 + wn * 16;
    const unsigned short* BT = isM ? Wc1bT : W1bT;
    const float* bias = isM ? bcomb1 : b1;
    float* C = isM ? M1f : h1;
    const int ldc = isM ? 128 : 256;
    const int lrow = wr * 16 + r;
    const int bcol = colBase + r;
    const unsigned short* Bp = BT + (size_t)bcol * 288 + g * 8;
    f32x4 acc0 = {0.f, 0.f, 0.f, 0.f}, acc1 = {0.f, 0.f, 0.f, 0.f};
#pragma unroll
    for (int k0 = 0; k0 < 288; k0 += 64) {
        acc0 = MFMA(*(const short8*)&sm.hm.At[lrow][k0 + g * 8],
                    *(const short8*)(Bp + k0), acc0);
        if (k0 + 32 < 288)
            acc1 = MFMA(*(const short8*)&sm.hm.At[lrow][k0 + 32 + g * 8],
                        *(const short8*)(Bp + k0 + 32), acc1);
    }
    f32x4 acc = acc0 + acc1;
    const float bv = bias[bcol];
    const int orow0 = xt * 32 + wr * 16 + g * 4;
#pragma unroll
    for (int i = 0; i < 4; ++i)
        C[(size_t)(orow0 + i) * ldc + bcol] = acc[i] + bv;
}

// --------------------------------------------------------------------------
// final head row: LN + LeakyReLU + dot(Wf) + bf.
// --------------------------------------------------------------------------
__device__ __forceinline__ void final_row(SMem& sm, int row,
    const float* __restrict__ h1, const float* __restrict__ div1,
    const float* __restrict__ beta1, const float* __restrict__ Wf,
    const float* __restrict__ bf, float* __restrict__ out)
{
    const int t = threadIdx.x, lane = t & 63, w = t >> 6;
    const float v1 = h1[(size_t)row * 256 + t];
    const float v2 = (t < 10) ? div1[(size_t)row * 10 + t] : 0.f;
    float s = v1 + v2, q = v1 * v1 + v2 * v2;
#pragma unroll
    for (int m = 32; m > 0; m >>= 1) { s += __shfl_xor(s, m); q += __shfl_xor(q, m); }
    if (lane == 0) { sm.ln.rs[w] = s; sm.ln.rq[w] = q; }
    __syncthreads();
    const float tot  = sm.ln.rs[0] + sm.ln.rs[1] + sm.ln.rs[2] + sm.ln.rs[3];
    const float totq = sm.ln.rq[0] + sm.ln.rq[1] + sm.ln.rq[2] + sm.ln.rq[3];
    const float mean = tot * (1.f / 266.f);
    const float var  = totq * (1.f / 266.f) - mean * mean;
    const float inv  = rsqrtf(var + EPS);
    float d = lrelu((v1 - mean) * inv + beta1[t]) * Wf[t];
    if (t < 10) d += lrelu((v2 - mean) * inv + beta1[256 + t]) * Wf[256 + t];
#pragma unroll
    for (int m = 32; m > 0; m >>= 1) d += __shfl_xor(d, m);
    if (lane == 0) sm.ln.rd[w] = d;
    __syncthreads();
    if (t == 0) out[row] = sm.ln.rd[0] + sm.ln.rd[1] + sm.ln.rd[2] + sm.ln.rd[3] + bf[0];
    __syncthreads();
}

// --------------------------------------------------------------------------
// The cooperative mega-kernel: 256 blocks x 256 threads, 5 grid syncs.
// --------------------------------------------------------------------------
__global__ __launch_bounds__(256) void mega(
    const float* __restrict__ x,  const float* __restrict__ W0, const float* __restrict__ b0,
    const float* __restrict__ Wd0, const float* __restrict__ bd0, const float* __restrict__ beta0,
    const float* __restrict__ W1, const float* __restrict__ b1,
    const float* __restrict__ Wd1, const float* __restrict__ bd1, const float* __restrict__ beta1,
    const float* __restrict__ Wf, const float* __restrict__ bf,
    float* __restrict__ ws, float* __restrict__ out)
{
    __shared__ SMem sm;
    cg::grid_group grid = cg::this_grid();
    const int bid = blockIdx.x, t = threadIdx.x;

    // workspace layout
    float* h0     = ws;
    float* M0f    = h0 + 1024 * 256;
    float* h1     = M0f + 1024 * 128;
    float* M1f    = h1 + 1024 * 256;
    float* div0   = M1f + 1024 * 128;
    float* div1   = div0 + 1024 * 10;
    float* bcomb0 = div1 + 1024 * 10;
    float* bcomb1 = bcomb0 + 128;
    unsigned short* xb    = (unsigned short*)(bcomb1 + 128);
    unsigned short* W0bT  = xb + 1024 * 512;      // [256][512]
    unsigned short* W1bT  = W0bT + 256 * 512;     // [256][288]
    unsigned short* Wc0bT = W1bT + 256 * 288;     // [128][512]
    unsigned short* Wc1bT = Wc0bT + 128 * 512;    // [128][288]

    // ---------------- P1: conversions + Wc (fp32) + bcomb ----------------
    if (bid < 54) {
        const int tid = bid * 256 + t, NT = 54 * 256;
        for (int i = tid; i < 131072; i += NT) {           // xb via float4
            const float4 v = ((const float4*)x)[i];
            ushort4 o;
            o.x = f2bf(v.x); o.y = f2bf(v.y); o.z = f2bf(v.z); o.w = f2bf(v.w);
            ((ushort4*)xb)[i] = o;
        }
        for (int i = tid; i < 131072; i += NT) {           // W0bT [n][k]
            const int n = i >> 9, k = i & 511;
            W0bT[i] = f2bf(W0[k * 256 + n]);
        }
        for (int i = tid; i < 73728; i += NT) {            // W1bT [n][kk] (pad k>=266)
            const int n = i / 288, kk = i - n * 288;
            W1bT[i] = (kk < 266) ? f2bf(W1[kk * 256 + n]) : (unsigned short)0;
        }
    } else if (bid < 56) {
        const float* bb = (bid == 54) ? b0 : b1;
        const float* Wd = (bid == 54) ? Wd0 : Wd1;
        const float* bd = (bid == 54) ? bd0 : bd1;
        float* o = (bid == 54) ? bcomb0 : bcomb1;
        if (t < 128) {
            float s = 0.f;
            if (t < 100) {
                s = bd[t];
#pragma unroll 4
                for (int k = 0; k < 256; ++k) s += bb[k] * Wd[k * 100 + t];
            }
            o[t] = s;
        }
    } else {
        // Wc rows: 800 virtual rows (512 Wc0 + 288 Wc1); 4 rows per block.
        const int half = t >> 7, c = t & 127;
        const int base = (bid - 56) * 4 + half * 2;
        for (int rr = 0; rr < 2; ++rr) {
            const int row = base + rr;
            if (row < 512) {
                float s = 0.f;
                if (c < 100) {
                    const float* wp = W0 + row * 256;
                    const float* dp = Wd0 + c;
#pragma unroll 4
                    for (int k = 0; k < 256; ++k) s += wp[k] * dp[k * 100];
                }
                Wc0bT[c * 512 + row] = f2bf(s);
            } else {
                const int a = row - 512;
                float s = 0.f;
                if (c < 100 && a < 266) {
                    const float* wp = W1 + a * 256;
                    const float* dp = Wd1 + c;
#pragma unroll 4
                    for (int k = 0; k < 256; ++k) s += wp[k] * dp[k * 100];
                }
                Wc1bT[c * 288 + a] = f2bf(s);
            }
        }
    }
    grid.sync();

    // ---------------- P2: hm0 (h0 = x@W0+b0 || M0 = x@Wc0+bcomb0) --------
    {
        const int xt = bid & 31, yt = bid >> 5;
        hm_tile_global(xb, 512, xt, yt, W0bT, b0, h0, Wc0bT, bcomb0, M0f);
        if (bid < 128)
            hm_tile_global(xb, 512, xt, 8 + (bid >> 5), W0bT, b0, h0, Wc0bT, bcomb0, M0f);
    }
    grid.sync();

    // ---------------- P3: diversity 0 ------------------------------------
    {
        const int rt = bid & 31;
        div_job(sm, M0f, div0, rt, bid >> 5);
        if (bid < 64) div_job(sm, M0f, div0, rt, 8 + (bid >> 5));
    }
    grid.sync();

    // ---------------- P4: LN0 (fused) + hm1 ------------------------------
    {
        const int xt = bid & 31, yt = bid >> 5;
        ln_stage(sm, xt, h0, div0, beta0);
        __syncthreads();
        hm1_pass(sm, xt, yt, W1bT, b1, h1, Wc1bT, bcomb1, M1f);
        if (bid < 128)
            hm1_pass(sm, xt, 8 + (bid >> 5), W1bT, b1, h1, Wc1bT, bcomb1, M1f);
    }
    grid.sync();

    // ---------------- P5: diversity 1 ------------------------------------
    {
        const int rt = bid & 31;
        div_job(sm, M1f, div1, rt, bid >> 5);
        if (bid < 64) div_job(sm, M1f, div1, rt, 8 + (bid >> 5));
    }
    grid.sync();

    // ---------------- P6: LN1 + head -------------------------------------
    for (int rep = 0; rep < 4; ++rep)
        final_row(sm, bid + rep * 256, h1, div1, beta1, Wf, bf, out);
}

// --------------------------------------------------------------------------
extern "C" void kernel_launch(void* const* d_in, const int* in_sizes, int n_in,
                              void* d_out, int out_size, void* d_ws, size_t ws_size,
                              hipStream_t stream)
{
    const float* x     = (const float*)d_in[0];
    const float* W0    = (const float*)d_in[1];
    const float* b0    = (const float*)d_in[2];
    const float* Wd0   = (const float*)d_in[3];
    const float* bd0   = (const float*)d_in[4];
    const float* beta0 = (const float*)d_in[5];
    const float* W1    = (const float*)d_in[6];
    const float* b1    = (const float*)d_in[7];
    const float* Wd1   = (const float*)d_in[8];
    const float* bd1   = (const float*)d_in[9];
    const float* beta1 = (const float*)d_in[10];
    const float* Wf    = (const float*)d_in[11];
    const float* bf    = (const float*)d_in[12];
    float* ws  = (float*)d_ws;
    float* out = (float*)d_out;

    void* args[] = {
        (void*)&x,  (void*)&W0, (void*)&b0, (void*)&Wd0, (void*)&bd0, (void*)&beta0,
        (void*)&W1, (void*)&b1, (void*)&Wd1, (void*)&bd1, (void*)&beta1,
        (void*)&Wf, (void*)&bf, (void*)&ws, (void*)&out
    };
    hipLaunchCooperativeKernel(reinterpret_cast<void*>(mega),
                               dim3(256), dim3(256), args, 0, stream);
}

// Round 5
// 86.044 us; speedup vs baseline: 3.1535x; 3.1535x over previous
//
#include <hip/hip_runtime.h>

typedef __attribute__((ext_vector_type(8))) short short8;
typedef __attribute__((ext_vector_type(4))) float f32x4;

#define EPS   1e-3f
#define ALPHA 0.3f

#define MFMA(a, b, c) __builtin_amdgcn_mfma_f32_16x16x32_bf16((a), (b), (c), 0, 0, 0)

__device__ __forceinline__ unsigned short f2bf(float f) {
    unsigned u = __float_as_uint(f);
    unsigned r = u + 0x7FFFu + ((u >> 16) & 1u);
    return (unsigned short)(r >> 16);
}
__device__ __forceinline__ float lrelu(float v) { return v > 0.f ? v : ALPHA * v; }

// ---------------------------------------------------------------------------
// PREP (1 launch, 308 blocks):
//   bid   0..31 : W0 -> W0bT [256n][512k] bf16, LDS-tiled transpose
//   bid  32..51 : W1 -> W1bT [256n][288k] bf16 (k>=266 zero), transpose
//   bid  52..105: x  -> xb   [1024][512]  bf16, float4 coalesced
//   bid 106..305: WcT fp32:  Wc0bT [128c][512f], Wc1bT [128c][288a]
//   bid 306..307: bcomb = b@Wd + bd  (128 wide, zero-padded)
// ---------------------------------------------------------------------------
__global__ __launch_bounds__(256) void prep_kernel(
    const float* __restrict__ x,
    const float* __restrict__ W0, const float* __restrict__ Wd0,
    const float* __restrict__ W1, const float* __restrict__ Wd1,
    const float* __restrict__ b0, const float* __restrict__ bd0,
    const float* __restrict__ b1, const float* __restrict__ bd1,
    unsigned short* __restrict__ xb,
    unsigned short* __restrict__ W0bT, unsigned short* __restrict__ W1bT,
    unsigned short* __restrict__ Wc0bT, unsigned short* __restrict__ Wc1bT,
    float* __restrict__ bcomb0, float* __restrict__ bcomb1)
{
    __shared__ float Tile[64][65];
    const int bid = blockIdx.x, t = threadIdx.x;
    const int lane = t & 63, w4 = t >> 6;

    if (bid < 32) {                       // --- W0 transpose tile (64k x 64n)
        const int kt = bid & 7, nt = bid >> 3;
#pragma unroll
        for (int rr = 0; rr < 16; ++rr) {
            const int r = rr * 4 + w4;    // local k
            Tile[r][lane] = W0[(size_t)(kt * 64 + r) * 256 + nt * 64 + lane];
        }
        __syncthreads();
#pragma unroll
        for (int rr = 0; rr < 16; ++rr) {
            const int r = rr * 4 + w4;    // local n
            W0bT[(size_t)(nt * 64 + r) * 512 + kt * 64 + lane] = f2bf(Tile[lane][r]);
        }
    } else if (bid < 52) {                // --- W1 transpose tile (64k x 64n)
        const int idx = bid - 32;
        const int kt = idx % 5, nt = idx / 5;
#pragma unroll
        for (int rr = 0; rr < 16; ++rr) {
            const int r = rr * 4 + w4;
            const int gk = kt * 64 + r;   // concat-dim index
            Tile[r][lane] = (gk < 266) ? W1[(size_t)gk * 256 + nt * 64 + lane] : 0.f;
        }
        __syncthreads();
#pragma unroll
        for (int rr = 0; rr < 16; ++rr) {
            const int r = rr * 4 + w4;    // local n
            const int kk = kt * 64 + lane;
            if (kk < 288)
                W1bT[(size_t)(nt * 64 + r) * 288 + kk] = f2bf(Tile[lane][r]);
        }
    } else if (bid < 106) {               // --- xb conversion (float4)
        const int tid = (bid - 52) * 256 + t, NT = 54 * 256;
        for (int i = tid; i < 131072; i += NT) {
            const float4 v = ((const float4*)x)[i];
            ushort4 o;
            o.x = f2bf(v.x); o.y = f2bf(v.y); o.z = f2bf(v.z); o.w = f2bf(v.w);
            ((ushort4*)xb)[i] = o;
        }
    } else if (bid < 306) {               // --- Wc rows (fp32 accumulate)
        const int half = t >> 7, c = t & 127;
        const int base = (bid - 106) * 4 + half * 2;
#pragma unroll
        for (int rr = 0; rr < 2; ++rr) {
            const int row = base + rr;
            if (row < 512) {
                float s = 0.f;
                if (c < 100) {
                    const float* wp = W0 + (size_t)row * 256;
                    const float* dp = Wd0 + c;
#pragma unroll 4
                    for (int k = 0; k < 256; ++k) s += wp[k] * dp[k * 100];
                }
                Wc0bT[(size_t)c * 512 + row] = f2bf(s);
            } else {
                const int a = row - 512;
                float s = 0.f;
                if (c < 100 && a < 266) {
                    const float* wp = W1 + (size_t)a * 256;
                    const float* dp = Wd1 + c;
#pragma unroll 4
                    for (int k = 0; k < 256; ++k) s += wp[k] * dp[k * 100];
                }
                Wc1bT[(size_t)c * 288 + a] = f2bf(s);
            }
        }
    } else {                              // --- bcomb
        const float* bb = (bid == 306) ? b0 : b1;
        const float* Wd = (bid == 306) ? Wd0 : Wd1;
        const float* bd = (bid == 306) ? bd0 : bd1;
        float* o = (bid == 306) ? bcomb0 : bcomb1;
        if (t < 128) {
            float s = 0.f;
            if (t < 100) {
                s = bd[t];
#pragma unroll 4
                for (int k = 0; k < 256; ++k) s += bb[k] * Wd[k * 100 + t];
            }
            o[t] = s;
        }
    }
}

// ---------------------------------------------------------------------------
// hm0: fused h-GEMM + M-GEMM. grid (32, 12):
//   by<8 : h0[1024][256] = xb @ W0bT^T + b0
//   by>=8: M0[1024][128] = xb @ Wc0bT^T + bcomb0
// One 16x16 C-tile per wave, fragments straight from L2.
// ---------------------------------------------------------------------------
__global__ __launch_bounds__(256) void hm_mfma(
    const unsigned short* __restrict__ A, int ldk,
    const unsigned short* __restrict__ BTh, const float* __restrict__ biash,
    float* __restrict__ Ch,
    const unsigned short* __restrict__ BTm, const float* __restrict__ biasm,
    float* __restrict__ Cm)
{
    const int t = threadIdx.x, lane = t & 63, w = t >> 6;
    const int wr = w >> 1, wn = w & 1, r = lane & 15, g = lane >> 4;
    const bool isM = blockIdx.y >= 8;
    const int colBase = (isM ? (int)blockIdx.y - 8 : (int)blockIdx.y) * 32 + wn * 16;
    const unsigned short* BT = isM ? BTm : BTh;
    const float* bias = isM ? biasm : biash;
    float* C = isM ? Cm : Ch;
    const int ldc = isM ? 128 : 256;

    const int arow = blockIdx.x * 32 + wr * 16 + r;
    const int bcol = colBase + r;
    const unsigned short* Ap = A + (size_t)arow * ldk + g * 8;
    const unsigned short* Bp = BT + (size_t)bcol * ldk + g * 8;

    f32x4 acc0 = {0.f, 0.f, 0.f, 0.f}, acc1 = {0.f, 0.f, 0.f, 0.f};
#pragma unroll 4
    for (int k0 = 0; k0 < ldk; k0 += 64) {
        acc0 = MFMA(*(const short8*)(Ap + k0),      *(const short8*)(Bp + k0),      acc0);
        acc1 = MFMA(*(const short8*)(Ap + k0 + 32), *(const short8*)(Bp + k0 + 32), acc1);
    }
    f32x4 acc = acc0 + acc1;
    const float bv = bias[bcol];
    const int orow0 = blockIdx.x * 32 + wr * 16 + g * 4;
#pragma unroll
    for (int i = 0; i < 4; ++i)
        C[(size_t)(orow0 + i) * ldc + bcol] = acc[i] + bv;
}

// ---------------------------------------------------------------------------
// diversity: div[i][k] = sum_j exp(-L1(M[i,k*10:+10], M[j,...])).
// grid (32,10), 256 thr: 32 rows x 8 j-chunks. LDS slice [1024][12].
// ---------------------------------------------------------------------------
__global__ __launch_bounds__(256) void diversity_kernel(
    const float* __restrict__ M, float* __restrict__ divOut)
{
    __shared__ float Ms[1024 * 12];
    __shared__ float red[256];

    const int k = blockIdx.y;
    const int t = threadIdx.x;

    for (int idx = t; idx < 1024 * 5; idx += 256) {
        const int j = idx / 5;
        const int dd = idx - j * 5;
        const float2 v = *(const float2*)&M[(size_t)j * 128 + k * 10 + dd * 2];
        Ms[j * 12 + dd * 2]     = v.x;
        Ms[j * 12 + dd * 2 + 1] = v.y;
    }
    __syncthreads();

    const int il = t & 31, jc = t >> 5;
    const int i = blockIdx.x * 32 + il;

    float Mi[10];
#pragma unroll
    for (int d = 0; d < 10; ++d) Mi[d] = Ms[i * 12 + d];

    float acc = 0.f;
    const int jB = jc * 128;
#pragma unroll 2
    for (int j = jB; j < jB + 128; ++j) {
        const float4 v0 = *(const float4*)&Ms[j * 12];
        const float4 v1 = *(const float4*)&Ms[j * 12 + 4];
        const float2 v2 = *(const float2*)&Ms[j * 12 + 8];
        float l1 = fabsf(Mi[0] - v0.x) + fabsf(Mi[1] - v0.y)
                 + fabsf(Mi[2] - v0.z) + fabsf(Mi[3] - v0.w)
                 + fabsf(Mi[4] - v1.x) + fabsf(Mi[5] - v1.y)
                 + fabsf(Mi[6] - v1.z) + fabsf(Mi[7] - v1.w)
                 + fabsf(Mi[8] - v2.x) + fabsf(Mi[9] - v2.y);
        acc += __expf(-l1);
    }

    red[t] = acc;
    __syncthreads();
    if (t < 32) {
        float s = 0.f;
#pragma unroll
        for (int c = 0; c < 8; ++c) s += red[c * 32 + t];
        divOut[(size_t)(blockIdx.x * 32 + t) * 10 + k] = s;
    }
}

// ---------------------------------------------------------------------------
// hm1 with fused LN0: each block LNs its 32 A-rows (from h0/div0) into an LDS
// bf16 tile [32][296] (cols 266..287 zeroed), then MFMAs over K=288.
// grid (32, 12): by<8 -> h1 (256 cols), by>=8 -> M1 (128 cols).
// ---------------------------------------------------------------------------
__global__ __launch_bounds__(256) void hm1_lnfused(
    const float* __restrict__ h0, const float* __restrict__ div0,
    const float* __restrict__ beta0,
    const unsigned short* __restrict__ W1bT, const float* __restrict__ b1,
    float* __restrict__ h1,
    const unsigned short* __restrict__ Wc1bT, const float* __restrict__ bcomb1,
    float* __restrict__ M1f)
{
    __shared__ unsigned short At[32][296];

    const int t = threadIdx.x, lane = t & 63, w = t >> 6;
    const int xt = blockIdx.x;

    // --- LN0 stage: wave w handles rows w*8..w*8+7 ---
#pragma unroll 2
    for (int rr = 0; rr < 8; ++rr) {
        const int r = xt * 32 + w * 8 + rr;
        const float hv0 = h0[(size_t)r * 256 + lane];
        const float hv1 = h0[(size_t)r * 256 + 64 + lane];
        const float hv2 = h0[(size_t)r * 256 + 128 + lane];
        const float hv3 = h0[(size_t)r * 256 + 192 + lane];
        const float dvv = (lane < 10) ? div0[(size_t)r * 10 + lane] : 0.f;
        float s = hv0 + hv1 + hv2 + hv3 + dvv;
        float q = hv0 * hv0 + hv1 * hv1 + hv2 * hv2 + hv3 * hv3 + dvv * dvv;
#pragma unroll
        for (int m = 32; m > 0; m >>= 1) { s += __shfl_xor(s, m); q += __shfl_xor(q, m); }
        const float mean = s * (1.f / 266.f);
        const float var  = q * (1.f / 266.f) - mean * mean;
        const float inv  = rsqrtf(var + EPS);
        const int lr = w * 8 + rr;
        At[lr][lane]       = f2bf(lrelu((hv0 - mean) * inv + beta0[lane]));
        At[lr][64 + lane]  = f2bf(lrelu((hv1 - mean) * inv + beta0[64 + lane]));
        At[lr][128 + lane] = f2bf(lrelu((hv2 - mean) * inv + beta0[128 + lane]));
        At[lr][192 + lane] = f2bf(lrelu((hv3 - mean) * inv + beta0[192 + lane]));
        if (lane < 10)
            At[lr][256 + lane] = f2bf(lrelu((dvv - mean) * inv + beta0[256 + lane]));
        else if (lane < 32)
            At[lr][256 + lane] = 0;
    }
    __syncthreads();

    // --- MFMA pass over K=288 ---
    const int wr = w >> 1, wn = w & 1, r = lane & 15, g = lane >> 4;
    const bool isM = blockIdx.y >= 8;
    const int colBase = (isM ? (int)blockIdx.y - 8 : (int)blockIdx.y) * 32 + wn * 16;
    const unsigned short* BT = isM ? Wc1bT : W1bT;
    const float* bias = isM ? bcomb1 : b1;
    float* C = isM ? M1f : h1;
    const int ldc = isM ? 128 : 256;
    const int lrow = wr * 16 + r;
    const int bcol = colBase + r;
    const unsigned short* Bp = BT + (size_t)bcol * 288 + g * 8;

    f32x4 acc0 = {0.f, 0.f, 0.f, 0.f}, acc1 = {0.f, 0.f, 0.f, 0.f};
#pragma unroll
    for (int k0 = 0; k0 < 288; k0 += 64) {
        acc0 = MFMA(*(const short8*)&At[lrow][k0 + g * 8],
                    *(const short8*)(Bp + k0), acc0);
        if (k0 + 32 < 288)
            acc1 = MFMA(*(const short8*)&At[lrow][k0 + 32 + g * 8],
                        *(const short8*)(Bp + k0 + 32), acc1);
    }
    f32x4 acc = acc0 + acc1;
    const float bv = bias[bcol];
    const int orow0 = xt * 32 + wr * 16 + g * 4;
#pragma unroll
    for (int i = 0; i < 4; ++i)
        C[(size_t)(orow0 + i) * ldc + bcol] = acc[i] + bv;
}

// ---------------------------------------------------------------------------
// LN1 + LeakyReLU + final dot with Wf. One block per row.
// ---------------------------------------------------------------------------
__global__ __launch_bounds__(256) void ln_final(
    const float* __restrict__ h, const float* __restrict__ divIn,
    const float* __restrict__ beta, const float* __restrict__ Wf,
    const float* __restrict__ bf, float* __restrict__ out)
{
    const int row = blockIdx.x;
    const int t = threadIdx.x;

    const float v1 = h[(size_t)row * 256 + t];
    const float v2 = (t < 10) ? divIn[(size_t)row * 10 + t] : 0.f;

    float s = v1 + v2, q = v1 * v1 + v2 * v2;

    __shared__ float rs[4], rq[4], rd[4];
#pragma unroll
    for (int m = 32; m > 0; m >>= 1) { s += __shfl_xor(s, m); q += __shfl_xor(q, m); }
    const int lane = t & 63, w = t >> 6;
    if (lane == 0) { rs[w] = s; rq[w] = q; }
    __syncthreads();

    const float tot  = rs[0] + rs[1] + rs[2] + rs[3];
    const float totq = rq[0] + rq[1] + rq[2] + rq[3];
    const float mean = tot * (1.f / 266.f);
    const float var  = totq * (1.f / 266.f) - mean * mean;
    const float inv  = rsqrtf(var + EPS);

    float d = lrelu((v1 - mean) * inv + beta[t]) * Wf[t];
    if (t < 10) d += lrelu((v2 - mean) * inv + beta[256 + t]) * Wf[256 + t];
#pragma unroll
    for (int m = 32; m > 0; m >>= 1) d += __shfl_xor(d, m);
    if (lane == 0) rd[w] = d;
    __syncthreads();
    if (t == 0) out[row] = rd[0] + rd[1] + rd[2] + rd[3] + bf[0];
}

// ---------------------------------------------------------------------------
extern "C" void kernel_launch(void* const* d_in, const int* in_sizes, int n_in,
                              void* d_out, int out_size, void* d_ws, size_t ws_size,
                              hipStream_t stream)
{
    const float* x     = (const float*)d_in[0];
    const float* W0    = (const float*)d_in[1];
    const float* b0    = (const float*)d_in[2];
    const float* Wd0   = (const float*)d_in[3];
    const float* bd0   = (const float*)d_in[4];
    const float* beta0 = (const float*)d_in[5];
    const float* W1    = (const float*)d_in[6];
    const float* b1    = (const float*)d_in[7];
    const float* Wd1   = (const float*)d_in[8];
    const float* bd1   = (const float*)d_in[9];
    const float* beta1 = (const float*)d_in[10];
    const float* Wf    = (const float*)d_in[11];
    const float* bf    = (const float*)d_in[12];
    float* out = (float*)d_out;

    float* fws = (float*)d_ws;
    float* h0     = fws;                       // 1024*256
    float* M0f    = h0 + 1024 * 256;           // 1024*128
    float* h1     = M0f + 1024 * 128;          // 1024*256
    float* M1f    = h1 + 1024 * 256;           // 1024*128
    float* div0   = M1f + 1024 * 128;          // 1024*10
    float* div1   = div0 + 1024 * 10;          // 1024*10
    float* bcomb0 = div1 + 1024 * 10;          // 128
    float* bcomb1 = bcomb0 + 128;              // 128
    unsigned short* xb    = (unsigned short*)(bcomb1 + 128);
    unsigned short* W0bT  = xb + 1024 * 512;   // [256][512]
    unsigned short* W1bT  = W0bT + 256 * 512;  // [256][288]
    unsigned short* Wc0bT = W1bT + 256 * 288;  // [128][512]
    unsigned short* Wc1bT = Wc0bT + 128 * 512; // [128][288]

    dim3 blk(256);

    // 1. prep: conversions + transposes + Wc (fp32) + bcomb
    prep_kernel<<<dim3(308), blk, 0, stream>>>(
        x, W0, Wd0, W1, Wd1, b0, bd0, b1, bd1,
        xb, W0bT, W1bT, Wc0bT, Wc1bT, bcomb0, bcomb1);

    // 2. h0 = x@W0+b0 || M0 = x@Wc0+bcomb0
    hm_mfma<<<dim3(32, 12), blk, 0, stream>>>(
        xb, 512, W0bT, b0, h0, Wc0bT, bcomb0, M0f);

    // 3. diversity 0
    diversity_kernel<<<dim3(32, 10), blk, 0, stream>>>(M0f, div0);

    // 4. LN0 (fused) + h1/M1 GEMMs
    hm1_lnfused<<<dim3(32, 12), blk, 0, stream>>>(
        h0, div0, beta0, W1bT, b1, h1, Wc1bT, bcomb1, M1f);

    // 5. diversity 1
    diversity_kernel<<<dim3(32, 10), blk, 0, stream>>>(M1f, div1);

    // 6. LN1 + head
    ln_final<<<dim3(1024), blk, 0, stream>>>(h1, div1, beta1, Wf, bf, out);
}

// Round 6
// 75.987 us; speedup vs baseline: 3.5709x; 1.1324x over previous
//
#include <hip/hip_runtime.h>

typedef __attribute__((ext_vector_type(8))) short short8;
typedef __attribute__((ext_vector_type(4))) float f32x4;

#define EPS   1e-3f
#define ALPHA 0.3f

#define MFMA(a, b, c) __builtin_amdgcn_mfma_f32_16x16x32_bf16((a), (b), (c), 0, 0, 0)

__device__ __forceinline__ unsigned short f2bf(float f) {
    unsigned u = __float_as_uint(f);
    unsigned r = u + 0x7FFFu + ((u >> 16) & 1u);
    return (unsigned short)(r >> 16);
}
__device__ __forceinline__ float lrelu(float v) { return v > 0.f ? v : ALPHA * v; }

// ---------------------------------------------------------------------------
// PREP (204 blocks):
//   bid 0..201 : Wc rows. 808 virtual rows = Wc0bT 512 + Wc1bT 296.
//                Wc0bT[c][k]: [128][512] bf16 ; Wc1bT[c][a]: [128][296] bf16.
//                4 partial accumulators to break the serial FMA chain.
//   bid 202/203: bcomb = b@Wd + bd (128 wide, zero-padded).
// ---------------------------------------------------------------------------
__global__ __launch_bounds__(256) void prep_kernel(
    const float* __restrict__ W0, const float* __restrict__ Wd0,
    const float* __restrict__ W1, const float* __restrict__ Wd1,
    const float* __restrict__ b0, const float* __restrict__ bd0,
    const float* __restrict__ b1, const float* __restrict__ bd1,
    unsigned short* __restrict__ Wc0bT, unsigned short* __restrict__ Wc1bT,
    float* __restrict__ bcomb0, float* __restrict__ bcomb1)
{
    const int bid = blockIdx.x, t = threadIdx.x;
    if (bid < 202) {
        const int half = t >> 7, c = t & 127;
        const int base = bid * 4 + half * 2;
#pragma unroll
        for (int rr = 0; rr < 2; ++rr) {
            const int row = base + rr;
            if (row < 512) {
                float s = 0.f;
                if (c < 100) {
                    const float* wp = W0 + (size_t)row * 256;
                    const float* dp = Wd0 + c;
                    float s0 = 0.f, s1 = 0.f, s2 = 0.f, s3 = 0.f;
                    for (int k = 0; k < 256; k += 4) {
                        s0 += wp[k]     * dp[k * 100];
                        s1 += wp[k + 1] * dp[(k + 1) * 100];
                        s2 += wp[k + 2] * dp[(k + 2) * 100];
                        s3 += wp[k + 3] * dp[(k + 3) * 100];
                    }
                    s = (s0 + s1) + (s2 + s3);
                }
                Wc0bT[(size_t)c * 512 + row] = f2bf(s);
            } else {
                const int a = row - 512;           // 0..295
                float s = 0.f;
                if (c < 100 && a < 266) {
                    const float* wp = W1 + (size_t)a * 256;
                    const float* dp = Wd1 + c;
                    float s0 = 0.f, s1 = 0.f, s2 = 0.f, s3 = 0.f;
                    for (int k = 0; k < 256; k += 4) {
                        s0 += wp[k]     * dp[k * 100];
                        s1 += wp[k + 1] * dp[(k + 1) * 100];
                        s2 += wp[k + 2] * dp[(k + 2) * 100];
                        s3 += wp[k + 3] * dp[(k + 3) * 100];
                    }
                    s = (s0 + s1) + (s2 + s3);
                }
                Wc1bT[(size_t)c * 296 + a] = f2bf(s);
            }
        }
    } else {
        const float* bb = (bid == 202) ? b0 : b1;
        const float* Wd = (bid == 202) ? Wd0 : Wd1;
        const float* bd = (bid == 202) ? bd0 : bd1;
        float* o = (bid == 202) ? bcomb0 : bcomb1;
        if (t < 128) {
            float s = 0.f;
            if (t < 100) {
                s = bd[t];
                float s0 = 0.f, s1 = 0.f;
                for (int k = 0; k < 256; k += 2) {
                    s0 += bb[k] * Wd[k * 100 + t];
                    s1 += bb[k + 1] * Wd[(k + 1) * 100 + t];
                }
                s += s0 + s1;
            }
            o[t] = s;
        }
    }
}

// ---------------------------------------------------------------------------
// hm0: grid (32,12). A = x (fp32, converted inline) staged to LDS [32][520];
// B: yt<8 -> W0 col-block transposed into LDS; yt>=8 -> Wc0bT rows copied.
// Then pure LDS+MFMA over K=512. Outputs h0 [1024][256] and Mt0 [10][1024][16].
// ---------------------------------------------------------------------------
__global__ __launch_bounds__(256) void hm0_mfma(
    const float* __restrict__ x, const float* __restrict__ W0,
    const unsigned short* __restrict__ Wc0bT,
    const float* __restrict__ b0, const float* __restrict__ bcomb0,
    float* __restrict__ h0, float* __restrict__ Mt0)
{
    __shared__ unsigned short At[32][520];
    __shared__ unsigned short Bt[32][520];

    const int t = threadIdx.x, xt = blockIdx.x, yt = blockIdx.y;

    // --- A stage: x[32 rows][512] fp32 -> bf16 LDS. thread=(row,kc) ---
    {
        const int row = t >> 3, kc = t & 7;
        const float* xp = x + (size_t)(xt * 32 + row) * 512 + kc * 64;
#pragma unroll
        for (int i = 0; i < 8; ++i) {
            const float4 lo = ((const float4*)xp)[i * 2];
            const float4 hi = ((const float4*)xp)[i * 2 + 1];
            short8 p;
            p[0] = f2bf(lo.x); p[1] = f2bf(lo.y); p[2] = f2bf(lo.z); p[3] = f2bf(lo.w);
            p[4] = f2bf(hi.x); p[5] = f2bf(hi.y); p[6] = f2bf(hi.z); p[7] = f2bf(hi.w);
            *(short8*)&At[row][kc * 64 + i * 8] = p;
        }
    }
    // --- B stage ---
    if (yt < 8) {                       // transpose W0[512][256] col-block
        const int kc = t >> 5, n = t & 31, col0 = yt * 32;
        for (int kk = 0; kk < 64; kk += 2) {
            const int k = kc * 64 + kk;
            const float a = W0[(size_t)k * 256 + col0 + n];
            const float b = W0[(size_t)(k + 1) * 256 + col0 + n];
            const unsigned pk = (unsigned)f2bf(a) | ((unsigned)f2bf(b) << 16);
            *(unsigned*)&Bt[n][k] = pk;
        }
    } else {                            // copy Wc0bT rows (already k-major)
        const int c = t >> 3, kc = t & 7;
        const unsigned short* bp = Wc0bT + (size_t)((yt - 8) * 32 + c) * 512 + kc * 64;
#pragma unroll
        for (int i = 0; i < 8; ++i)
            *(short8*)&Bt[c][kc * 64 + i * 8] = ((const short8*)bp)[i];
    }
    __syncthreads();

    // --- MFMA K=512 ---
    const int lane = t & 63, w = t >> 6;
    const int wr = w >> 1, wn = w & 1, r = lane & 15, g = lane >> 4;
    const int lrA = wr * 16 + r, lrB = wn * 16 + r;
    f32x4 acc0 = {0.f, 0.f, 0.f, 0.f}, acc1 = {0.f, 0.f, 0.f, 0.f};
#pragma unroll
    for (int k0 = 0; k0 < 512; k0 += 64) {
        acc0 = MFMA(*(const short8*)&At[lrA][k0 + g * 8],
                    *(const short8*)&Bt[lrB][k0 + g * 8], acc0);
        acc1 = MFMA(*(const short8*)&At[lrA][k0 + 32 + g * 8],
                    *(const short8*)&Bt[lrB][k0 + 32 + g * 8], acc1);
    }
    const f32x4 acc = acc0 + acc1;
    const int orow0 = xt * 32 + wr * 16 + g * 4;

    if (yt < 8) {
        const int bcol = yt * 32 + wn * 16 + r;
        const float bv = b0[bcol];
#pragma unroll
        for (int i = 0; i < 4; ++i)
            h0[(size_t)(orow0 + i) * 256 + bcol] = acc[i] + bv;
    } else {
        const int c = (yt - 8) * 32 + wn * 16 + r;
        if (c < 100) {
            const int kq = c / 10, d = c - kq * 10;
            const float bv = bcomb0[c];
            float* dst = Mt0 + (size_t)kq * (1024 * 16) + (size_t)orow0 * 16 + d;
#pragma unroll
            for (int i = 0; i < 4; ++i) dst[i * 16] = acc[i] + bv;
        }
    }
}

// ---------------------------------------------------------------------------
// hm1: grid (32,12). A = a0b (bf16 [1024][296]) staged; B: yt<8 -> W1
// transposed (k<266, rest 0); yt>=8 -> Wc1bT rows. MFMA over K=288.
// ---------------------------------------------------------------------------
__global__ __launch_bounds__(256) void hm1_mfma(
    const unsigned short* __restrict__ a0b, const float* __restrict__ W1,
    const unsigned short* __restrict__ Wc1bT,
    const float* __restrict__ b1, const float* __restrict__ bcomb1,
    float* __restrict__ h1, float* __restrict__ Mt1)
{
    __shared__ unsigned short At[32][296];
    __shared__ unsigned short Bt[32][296];

    const int t = threadIdx.x, xt = blockIdx.x, yt = blockIdx.y;

    // --- A stage: copy a0b rows (37 short8 chunks per row) ---
    {
        const int row = t >> 3, kc = t & 7;
        const unsigned short* ap = a0b + (size_t)(xt * 32 + row) * 296;
        for (int i = kc; i < 37; i += 8)
            *(short8*)&At[row][i * 8] = ((const short8*)ap)[i];
    }
    // --- B stage ---
    if (yt < 8) {                       // transpose W1[266][256] col-block
        const int kc = t >> 5, n = t & 31, col0 = yt * 32;
        const int kkEnd = (kc == 7) ? 44 : 36;
        for (int kk = 0; kk < kkEnd; kk += 2) {
            const int k = kc * 36 + kk;
            const float a = (k < 266)     ? W1[(size_t)k * 256 + col0 + n] : 0.f;
            const float b = (k + 1 < 266) ? W1[(size_t)(k + 1) * 256 + col0 + n] : 0.f;
            const unsigned pk = (unsigned)f2bf(a) | ((unsigned)f2bf(b) << 16);
            *(unsigned*)&Bt[n][k] = pk;
        }
    } else {                            // copy Wc1bT rows
        const int c = t >> 3, kc = t & 7;
        const unsigned short* bp = Wc1bT + (size_t)((yt - 8) * 32 + c) * 296;
        for (int i = kc; i < 37; i += 8)
            *(short8*)&Bt[c][i * 8] = ((const short8*)bp)[i];
    }
    __syncthreads();

    // --- MFMA K=288 ---
    const int lane = t & 63, w = t >> 6;
    const int wr = w >> 1, wn = w & 1, r = lane & 15, g = lane >> 4;
    const int lrA = wr * 16 + r, lrB = wn * 16 + r;
    f32x4 acc0 = {0.f, 0.f, 0.f, 0.f}, acc1 = {0.f, 0.f, 0.f, 0.f};
#pragma unroll
    for (int k0 = 0; k0 < 256; k0 += 64) {
        acc0 = MFMA(*(const short8*)&At[lrA][k0 + g * 8],
                    *(const short8*)&Bt[lrB][k0 + g * 8], acc0);
        acc1 = MFMA(*(const short8*)&At[lrA][k0 + 32 + g * 8],
                    *(const short8*)&Bt[lrB][k0 + 32 + g * 8], acc1);
    }
    acc0 = MFMA(*(const short8*)&At[lrA][256 + g * 8],
                *(const short8*)&Bt[lrB][256 + g * 8], acc0);
    const f32x4 acc = acc0 + acc1;
    const int orow0 = xt * 32 + wr * 16 + g * 4;

    if (yt < 8) {
        const int bcol = yt * 32 + wn * 16 + r;
        const float bv = b1[bcol];
#pragma unroll
        for (int i = 0; i < 4; ++i)
            h1[(size_t)(orow0 + i) * 256 + bcol] = acc[i] + bv;
    } else {
        const int c = (yt - 8) * 32 + wn * 16 + r;
        if (c < 100) {
            const int kq = c / 10, d = c - kq * 10;
            const float bv = bcomb1[c];
            float* dst = Mt1 + (size_t)kq * (1024 * 16) + (size_t)orow0 * 16 + d;
#pragma unroll
            for (int i = 0; i < 4; ++i) dst[i * 16] = acc[i] + bv;
        }
    }
}

// ---------------------------------------------------------------------------
// diversity: grid (32,10). Mt slice [1024][16] staged fully coalesced.
// ---------------------------------------------------------------------------
__global__ __launch_bounds__(256) void diversity_kernel(
    const float* __restrict__ Mt, float* __restrict__ divOut)
{
    __shared__ float Ms[1024 * 16];
    __shared__ float red[256];

    const int t = threadIdx.x;
    const float* src = Mt + (size_t)blockIdx.y * (1024 * 16);
    for (int i = t; i < 1024 * 4; i += 256)
        ((float4*)Ms)[i] = ((const float4*)src)[i];
    __syncthreads();

    const int il = t & 31, jc = t >> 5;
    const int i = blockIdx.x * 32 + il;

    const float4 m0 = *(const float4*)&Ms[i * 16];
    const float4 m1 = *(const float4*)&Ms[i * 16 + 4];
    const float4 m2 = *(const float4*)&Ms[i * 16 + 8];

    float acc = 0.f;
    const int jB = jc * 128;
#pragma unroll 2
    for (int j = jB; j < jB + 128; ++j) {
        const float4 v0 = *(const float4*)&Ms[j * 16];
        const float4 v1 = *(const float4*)&Ms[j * 16 + 4];
        const float4 v2 = *(const float4*)&Ms[j * 16 + 8];
        float l1 = fabsf(m0.x - v0.x) + fabsf(m0.y - v0.y)
                 + fabsf(m0.z - v0.z) + fabsf(m0.w - v0.w)
                 + fabsf(m1.x - v1.x) + fabsf(m1.y - v1.y)
                 + fabsf(m1.z - v1.z) + fabsf(m1.w - v1.w)
                 + fabsf(m2.x - v2.x) + fabsf(m2.y - v2.y);
        acc += __expf(-l1);
    }

    red[t] = acc;
    __syncthreads();
    if (t < 32) {
        float s = 0.f;
#pragma unroll
        for (int c = 0; c < 8; ++c) s += red[c * 32 + t];
        divOut[(size_t)(blockIdx.x * 32 + t) * 10 + blockIdx.y] = s;
    }
}

// ---------------------------------------------------------------------------
// ln0: 256 blocks x 4 waves; one row per wave. LN + lrelu -> a0b [1024][296].
// ---------------------------------------------------------------------------
__global__ __launch_bounds__(256) void ln0_kernel(
    const float* __restrict__ h0, const float* __restrict__ div0,
    const float* __restrict__ beta0, unsigned short* __restrict__ a0b)
{
    const int t = threadIdx.x, lane = t & 63;
    const int row = blockIdx.x * 4 + (t >> 6);

    const float4 hv = ((const float4*)(h0 + (size_t)row * 256))[lane];
    const float dv = (lane < 10) ? div0[(size_t)row * 10 + lane] : 0.f;

    float s = hv.x + hv.y + hv.z + hv.w + dv;
    float q = hv.x * hv.x + hv.y * hv.y + hv.z * hv.z + hv.w * hv.w + dv * dv;
#pragma unroll
    for (int m = 32; m > 0; m >>= 1) { s += __shfl_xor(s, m); q += __shfl_xor(q, m); }

    const float mean = s * (1.f / 266.f);
    const float var  = q * (1.f / 266.f) - mean * mean;
    const float inv  = rsqrtf(var + EPS);

    const float4 bv = ((const float4*)beta0)[lane];
    ushort4 o;
    o.x = f2bf(lrelu((hv.x - mean) * inv + bv.x));
    o.y = f2bf(lrelu((hv.y - mean) * inv + bv.y));
    o.z = f2bf(lrelu((hv.z - mean) * inv + bv.z));
    o.w = f2bf(lrelu((hv.w - mean) * inv + bv.w));
    *(ushort4*)&a0b[(size_t)row * 296 + lane * 4] = o;

    if (lane < 10)
        a0b[(size_t)row * 296 + 256 + lane] = f2bf(lrelu((dv - mean) * inv + beta0[256 + lane]));
    else if (lane >= 16 && lane < 46)
        a0b[(size_t)row * 296 + 250 + lane] = 0;   // cols 266..295 zero
}

// ---------------------------------------------------------------------------
// ln_final: 256 blocks x 4 waves; one row per wave. LN + lrelu + dot(Wf)+bf.
// ---------------------------------------------------------------------------
__global__ __launch_bounds__(256) void ln_final(
    const float* __restrict__ h1, const float* __restrict__ div1,
    const float* __restrict__ beta1, const float* __restrict__ Wf,
    const float* __restrict__ bf, float* __restrict__ out)
{
    const int t = threadIdx.x, lane = t & 63;
    const int row = blockIdx.x * 4 + (t >> 6);

    const float4 hv = ((const float4*)(h1 + (size_t)row * 256))[lane];
    const float dv = (lane < 10) ? div1[(size_t)row * 10 + lane] : 0.f;

    float s = hv.x + hv.y + hv.z + hv.w + dv;
    float q = hv.x * hv.x + hv.y * hv.y + hv.z * hv.z + hv.w * hv.w + dv * dv;
#pragma unroll
    for (int m = 32; m > 0; m >>= 1) { s += __shfl_xor(s, m); q += __shfl_xor(q, m); }

    const float mean = s * (1.f / 266.f);
    const float var  = q * (1.f / 266.f) - mean * mean;
    const float inv  = rsqrtf(var + EPS);

    const float4 bv = ((const float4*)beta1)[lane];
    const float4 wf = ((const float4*)Wf)[lane];
    float d = lrelu((hv.x - mean) * inv + bv.x) * wf.x
            + lrelu((hv.y - mean) * inv + bv.y) * wf.y
            + lrelu((hv.z - mean) * inv + bv.z) * wf.z
            + lrelu((hv.w - mean) * inv + bv.w) * wf.w;
    if (lane < 10)
        d += lrelu((dv - mean) * inv + beta1[256 + lane]) * Wf[256 + lane];
#pragma unroll
    for (int m = 32; m > 0; m >>= 1) d += __shfl_xor(d, m);
    if (lane == 0) out[row] = d + bf[0];
}

// ---------------------------------------------------------------------------
extern "C" void kernel_launch(void* const* d_in, const int* in_sizes, int n_in,
                              void* d_out, int out_size, void* d_ws, size_t ws_size,
                              hipStream_t stream)
{
    const float* x     = (const float*)d_in[0];
    const float* W0    = (const float*)d_in[1];
    const float* b0    = (const float*)d_in[2];
    const float* Wd0   = (const float*)d_in[3];
    const float* bd0   = (const float*)d_in[4];
    const float* beta0 = (const float*)d_in[5];
    const float* W1    = (const float*)d_in[6];
    const float* b1    = (const float*)d_in[7];
    const float* Wd1   = (const float*)d_in[8];
    const float* bd1   = (const float*)d_in[9];
    const float* beta1 = (const float*)d_in[10];
    const float* Wf    = (const float*)d_in[11];
    const float* bf    = (const float*)d_in[12];
    float* out = (float*)d_out;

    float* fws = (float*)d_ws;
    float* h0     = fws;                        // 1024*256
    float* h1     = h0 + 1024 * 256;            // 1024*256
    float* Mt0    = h1 + 1024 * 256;            // 10*1024*16
    float* Mt1    = Mt0 + 10 * 1024 * 16;       // 10*1024*16
    float* div0   = Mt1 + 10 * 1024 * 16;       // 1024*10
    float* div1   = div0 + 1024 * 10;           // 1024*10
    float* bcomb0 = div1 + 1024 * 10;           // 128
    float* bcomb1 = bcomb0 + 128;               // 128
    unsigned short* Wc0bT = (unsigned short*)(bcomb1 + 128);  // [128][512]
    unsigned short* Wc1bT = Wc0bT + 128 * 512;                // [128][296]
    unsigned short* a0b   = Wc1bT + 128 * 296;                // [1024][296]

    dim3 blk(256);

    prep_kernel<<<dim3(204), blk, 0, stream>>>(
        W0, Wd0, W1, Wd1, b0, bd0, b1, bd1, Wc0bT, Wc1bT, bcomb0, bcomb1);

    hm0_mfma<<<dim3(32, 12), blk, 0, stream>>>(
        x, W0, Wc0bT, b0, bcomb0, h0, Mt0);

    diversity_kernel<<<dim3(32, 10), blk, 0, stream>>>(Mt0, div0);

    ln0_kernel<<<dim3(256), blk, 0, stream>>>(h0, div0, beta0, a0b);

    hm1_mfma<<<dim3(32, 12), blk, 0, stream>>>(
        a0b, W1, Wc1bT, b1, bcomb1, h1, Mt1);

    diversity_kernel<<<dim3(32, 10), blk, 0, stream>>>(Mt1, div1);

    ln_final<<<dim3(256), blk, 0, stream>>>(h1, div1, beta1, Wf, bf, out);
}